// Round 7
// baseline (3115.077 us; speedup 1.0000x reference)
//
#include <hip/hip_runtime.h>
#include <stdint.h>

#define B_    4096
#define H_    1024
#define T_    60
#define IN_   1028
#define KA_   1056      // IN_ padded to multiple of 32
#define G4_   4096      // 4*H
#define MLPH_ 64
#define NB_   6         // MLP batch depth / h ring size

typedef __attribute__((ext_vector_type(8))) short bf16x8;
typedef __attribute__((ext_vector_type(4))) float f32x4;
typedef __attribute__((ext_vector_type(4))) unsigned short u16x4;

#define GLOBAL_AS __attribute__((address_space(1)))
#define LDS_AS    __attribute__((address_space(3)))

__device__ __forceinline__ void gload_lds16(const void* g, void* l) {
  __builtin_amdgcn_global_load_lds((GLOBAL_AS void*)const_cast<void*>(g),
                                   (LDS_AS void*)l, 16, 0, 0);
}

__device__ __forceinline__ unsigned short f2bf(float f) {
  union { float f; unsigned int u; } v; v.f = f;
  unsigned int r = v.u + 0x7FFFu + ((v.u >> 16) & 1u);
  return (unsigned short)(r >> 16);
}

__device__ __forceinline__ float bf2f(unsigned short u) {
  union { unsigned int u; float f; } v; v.u = ((unsigned int)u) << 16;
  return v.f;
}

__device__ __forceinline__ float sigmf(float x) {
  float e = __expf(-x);
  return __builtin_amdgcn_rcpf(1.0f + e);
}

__device__ __forceinline__ float tanh_fast(float x) {
  x = fminf(fmaxf(x, -15.0f), 15.0f);
  float e = __expf(2.0f * x);
  return (e - 1.0f) * __builtin_amdgcn_rcpf(e + 1.0f);
}

// ---------------- conversion / setup kernels ----------------

__global__ void k_conv_bf16(const float* __restrict__ src,
                            unsigned short* __restrict__ dst, int n) {
  int i = blockIdx.x * blockDim.x + threadIdx.x;
  int stride = gridDim.x * blockDim.x;
  for (; i < n; i += stride) dst[i] = f2bf(src[i]);
}

// W_ih (4096 x 1028) -> bf16 padded (4096 x 1056)
__global__ void k_conv_wih(const float* __restrict__ w,
                           unsigned short* __restrict__ dst) {
  int i = blockIdx.x * blockDim.x + threadIdx.x;
  int stride = gridDim.x * blockDim.x;
  const int n = G4_ * KA_;
  for (; i < n; i += stride) {
    int r = i / KA_, k = i - r * KA_;
    dst[i] = (k < IN_) ? f2bf(w[(size_t)r * IN_ + k]) : (unsigned short)0;
  }
}

// z_aug = [z | last_pos | last_vel | zero-pad]  (4096 x 1056 bf16)
__global__ void k_build_zaug(const float* __restrict__ z,
                             const float* __restrict__ lp,
                             const float* __restrict__ lv,
                             unsigned short* __restrict__ dst) {
  int i = blockIdx.x * blockDim.x + threadIdx.x;
  int stride = gridDim.x * blockDim.x;
  const int n = B_ * KA_;
  for (; i < n; i += stride) {
    int b = i / KA_, k = i - b * KA_;
    float v;
    if (k < H_)            v = z[(size_t)b * H_ + k];
    else if (k < H_ + 2)   v = lp[b * 2 + (k - H_)];
    else if (k < IN_)      v = lv[b * 2 + (k - H_ - 2)];
    else                   v = 0.0f;
    dst[i] = f2bf(v);
  }
}

// ---------------- x_gates GEMM -> interleaved bf16x4 per (b, hc) ----------------
// round-4 structure (runs once, not hot). 16-row x 64B chunks, involution swizzle.

__global__ __launch_bounds__(256, 4) void k_xgates(
    const unsigned short* __restrict__ zaug, const unsigned short* __restrict__ wih,
    const float* __restrict__ bih, const float* __restrict__ bhh,
    u16x4* __restrict__ xg4) {
  __shared__ unsigned short As[2][128 * 32];
  __shared__ unsigned short Bs[2][128 * 32];
  const int tid = threadIdx.x, lane = tid & 63, wave = tid >> 6;
  const int bx = blockIdx.x, by = blockIdx.y;
  const int wm = wave >> 1, wn = wave & 1;
  const int rs = lane >> 2;
  const int c16 = (((lane & 3) ^ ((lane >> 3) & 3))) * 16;
  const int rdslot = ((lane >> 4) ^ ((lane >> 1) & 3)) * 8;

  const char* asrc0 = (const char*)zaug + ((size_t)(bx * 128 + (wave * 2 + 0) * 16 + rs) * KA_) * 2 + c16;
  const char* asrc1 = (const char*)zaug + ((size_t)(bx * 128 + (wave * 2 + 1) * 16 + rs) * KA_) * 2 + c16;
  const char* bsrc0 = (const char*)wih  + ((size_t)(wave * H_ + by * 32 +  0 + rs) * KA_) * 2 + c16;
  const char* bsrc1 = (const char*)wih  + ((size_t)(wave * H_ + by * 32 + 16 + rs) * KA_) * 2 + c16;

  f32x4 acc[4][4];   // [gate][m]
#pragma unroll
  for (int g = 0; g < 4; ++g)
#pragma unroll
    for (int m = 0; m < 4; ++m) acc[g][m] = {0.f, 0.f, 0.f, 0.f};

  gload_lds16(asrc0, &As[0][(wave * 2 + 0) * 512]);
  gload_lds16(asrc1, &As[0][(wave * 2 + 1) * 512]);
  gload_lds16(bsrc0, &Bs[0][(wave * 2 + 0) * 512]);
  gload_lds16(bsrc1, &Bs[0][(wave * 2 + 1) * 512]);
  __syncthreads();

  const int nt = KA_ / 32;
  int cur = 0;
  for (int kk = 0; kk < nt; ++kk) {
    if (kk + 1 < nt) {
      const size_t kb = (size_t)(kk + 1) * 64;
      gload_lds16(asrc0 + kb, &As[cur ^ 1][(wave * 2 + 0) * 512]);
      gload_lds16(asrc1 + kb, &As[cur ^ 1][(wave * 2 + 1) * 512]);
      gload_lds16(bsrc0 + kb, &Bs[cur ^ 1][(wave * 2 + 0) * 512]);
      gload_lds16(bsrc1 + kb, &Bs[cur ^ 1][(wave * 2 + 1) * 512]);
    }
    bf16x8 a[4], b[4];
#pragma unroll
    for (int m = 0; m < 4; ++m)
      a[m] = *(const bf16x8*)&As[cur][(wm * 64 + m * 16 + (lane & 15)) * 32 + rdslot];
#pragma unroll
    for (int g = 0; g < 4; ++g)
      b[g] = *(const bf16x8*)&Bs[cur][((g * 2 + wn) * 16 + (lane & 15)) * 32 + rdslot];
#pragma unroll
    for (int g = 0; g < 4; ++g)
#pragma unroll
      for (int m = 0; m < 4; ++m)
        acc[g][m] = __builtin_amdgcn_mfma_f32_16x16x32_bf16(a[m], b[g], acc[g][m], 0, 0, 0);
    __syncthreads();
    cur ^= 1;
  }

  const int r0 = (lane >> 4) * 4, cl = lane & 15;
  const int hc = by * 32 + wn * 16 + cl;
  const float bi = bih[hc]        + bhh[hc];
  const float bf = bih[1024 + hc] + bhh[1024 + hc];
  const float bg = bih[2048 + hc] + bhh[2048 + hc];
  const float bo = bih[3072 + hc] + bhh[3072 + hc];
#pragma unroll
  for (int m = 0; m < 4; ++m)
#pragma unroll
    for (int j = 0; j < 4; ++j) {
      int row = bx * 128 + wm * 64 + m * 16 + r0 + j;
      u16x4 st = {f2bf(acc[0][m][j] + bi), f2bf(acc[1][m][j] + bf),
                  f2bf(acc[2][m][j] + bg), f2bf(acc[3][m][j] + bo)};
      xg4[(size_t)row * H_ + hc] = st;
    }
}

// ---------------- LSTM step: 256-row quad-buffered 8-wave pipeline ----------------
// BM=256 rows, 64 hc x 4 gates (N=256), BK=32, grid (16,16)=256 blocks (1/CU),
// 512 threads = 8 waves (2 wm x 4 wn); wave = 128 rows x 16 hc x 4 gates.
// LDS: As[4][16KB] + Bs[4][16KB] = 128 KB. Quad buffer: tile kt lives in buf kt&3;
// tile kt+3 staged into buf (kt+3)&3 = buffer consumed at tile kt-1 -> no race,
// 3-tile prefetch lead. Ledger (gload instr/lane, 4/tile): prologue 12 (tiles
// 0,1,2). Tile kt p0: +2 (A of kt+3) -> 14 -> vmcnt(10) retires tile kt, leaves
// [kt+1:4][kt+2:4][kt+3A:2]. p1: +2 (B). Tail: kt=29/30/31 -> vmcnt(8/4/0).
// Row layout = round-4-proven: 64B rows, 4x16B slots, phys slot = s ^ (r&3),
// write-side via pre-swizzled global source (2-way read aliasing only = free).

__global__ __launch_bounds__(512, 1) void k_step(
    const unsigned short* __restrict__ hprev, const unsigned short* __restrict__ whh,
    const u16x4* __restrict__ xg4, float* __restrict__ cbuf,
    unsigned short* __restrict__ hout) {
  __shared__ unsigned short As[4][256 * 32];
  __shared__ unsigned short Bs[4][256 * 32];
  const int tid = threadIdx.x, lane = tid & 63, wave = tid >> 6;
  const int bx = blockIdx.x, by = blockIdx.y;
  const int wm = wave >> 2, wn = wave & 3;
  const int cl = lane & 15, sl16 = lane >> 4;

  // staging: half-tile o covers 128 rows; thread -> row o*128 + wave*16 + (lane>>2),
  // linear LDS slot lane&3, pre-swizzled global slot (lane&3)^((lane>>2)&3).
  const int srow = wave * 16 + (lane >> 2);
  const int sswz = ((lane & 3) ^ ((lane >> 2) & 3)) * 16;
  const char* agl = (const char*)hprev + (size_t)(bx * 256 + srow) * 2048 + sswz;
  const int hcl = (wave & 3) * 16 + (lane >> 2);
  const int glo = wave >> 2;                    // gate parity within half-tile
  const char* bgl = (const char*)whh + (size_t)(by * 64 + hcl) * 2048 + sswz;

  auto stA = [&](int kt, int c, int o) {
    gload_lds16(agl + (size_t)o * (128 * 2048) + (size_t)kt * 64,
                (char*)&As[c][0] + o * 8192 + wave * 1024);
  };
  auto stB = [&](int kt, int c, int o) {
    gload_lds16(bgl + ((size_t)(o * 2 + glo) << 21) + (size_t)kt * 64,
                (char*)&Bs[c][0] + o * 8192 + wave * 1024);
  };

  // fragment reads: row r -> byte r*64 + (sl16^(r&3))*16; r&3 == cl&3 for frag rows
  const int slot8 = (sl16 ^ (cl & 3)) * 8;
  const int aro = (wm * 128 + cl) * 32;
  const int bro = (wn * 16 + cl) * 32;

  f32x4 acc[4][8];   // [gate q][m-frag]
#pragma unroll
  for (int q = 0; q < 4; ++q)
#pragma unroll
    for (int m = 0; m < 8; ++m) acc[q][m] = {0.f, 0.f, 0.f, 0.f};

  bf16x8 a[4], b[4];

  // prologue: tiles 0,1,2 into bufs 0,1,2 (12 gloads/lane)
#pragma unroll
  for (int p = 0; p < 3; ++p) {
    stA(p, p, 0); stA(p, p, 1); stB(p, p, 0); stB(p, p, 1);
  }

  for (int kt = 0; kt < 32; ++kt) {
    const int c = kt & 3, sc = (kt + 3) & 3;
    const bool stg = (kt <= 28);
    // ---- phase 0 (m-frags 0..3) : tile boundary ----
    if (stg) { stA(kt + 3, sc, 0); stA(kt + 3, sc, 1); }
    if (kt <= 28)      asm volatile("s_waitcnt vmcnt(10)" ::: "memory");
    else if (kt == 29) asm volatile("s_waitcnt vmcnt(8)" ::: "memory");
    else if (kt == 30) asm volatile("s_waitcnt vmcnt(4)" ::: "memory");
    else               asm volatile("s_waitcnt vmcnt(0)" ::: "memory");
    __builtin_amdgcn_s_barrier();
#pragma unroll
    for (int q = 0; q < 4; ++q)
      b[q] = *(const bf16x8*)&Bs[c][bro + q * 2048 + slot8];
#pragma unroll
    for (int m = 0; m < 4; ++m)
      a[m] = *(const bf16x8*)&As[c][aro + m * 512 + slot8];
    __builtin_amdgcn_s_setprio(1);
#pragma unroll
    for (int q = 0; q < 4; ++q)
#pragma unroll
      for (int m = 0; m < 4; ++m)
        acc[q][m] = __builtin_amdgcn_mfma_f32_16x16x32_bf16(a[m], b[q], acc[q][m], 0, 0, 0);
    __builtin_amdgcn_s_setprio(0);
    __builtin_amdgcn_s_barrier();
    // ---- phase 1 (m-frags 4..7) ----
#pragma unroll
    for (int m = 0; m < 4; ++m)
      a[m] = *(const bf16x8*)&As[c][aro + (4 + m) * 512 + slot8];
    if (stg) { stB(kt + 3, sc, 0); stB(kt + 3, sc, 1); }
    __builtin_amdgcn_s_barrier();
    __builtin_amdgcn_s_setprio(1);
#pragma unroll
    for (int q = 0; q < 4; ++q)
#pragma unroll
      for (int m = 0; m < 4; ++m)
        acc[q][4 + m] = __builtin_amdgcn_mfma_f32_16x16x32_bf16(a[m], b[q], acc[q][4 + m], 0, 0, 0);
    __builtin_amdgcn_s_setprio(0);
    __builtin_amdgcn_s_barrier();
  }

  // epilogue: 32 cells/lane
  const int erow = bx * 256 + wm * 128 + sl16 * 4;
  const int hc = by * 64 + wn * 16 + cl;
#pragma unroll
  for (int m = 0; m < 8; ++m)
#pragma unroll
    for (int j = 0; j < 4; ++j) {
      size_t ci = (size_t)(erow + m * 16 + j) * H_ + hc;
      u16x4 xv = xg4[ci];
      float iv = sigmf(acc[0][m][j] + bf2f(xv[0]));
      float fv = sigmf(acc[1][m][j] + bf2f(xv[1]));
      float gv = tanh_fast(acc[2][m][j] + bf2f(xv[2]));
      float ov = sigmf(acc[3][m][j] + bf2f(xv[3]));
      float cv = fv * cbuf[ci] + iv * gv;
      cbuf[ci] = cv;
      hout[ci] = f2bf(ov * tanh_fast(cv));
    }
}

// ---------------- batched MLP over NB_ steps ----------------

__global__ __launch_bounds__(256) void k_mlp(
    const unsigned short* __restrict__ hring, const unsigned short* __restrict__ w1,
    const float* __restrict__ b1, const float* __restrict__ w2,
    const float* __restrict__ b2, float* __restrict__ delta, int t0) {
  __shared__ unsigned short As[64 * 32];
  __shared__ unsigned short Bs[64 * 32];
  __shared__ float hid[64][65];
  const int tid = threadIdx.x, lane = tid & 63, wave = tid >> 6;
  const int bx = blockIdx.x;
  const unsigned short* h = hring + (size_t)blockIdx.y * B_ * H_;
  const int t = t0 + blockIdx.y;
  const int rs = lane >> 2;
  const int c16 = (((lane & 3) ^ ((lane >> 3) & 3))) * 16;
  const int rdslot = ((lane >> 4) ^ ((lane >> 1) & 3)) * 8;

  f32x4 acc[4];
#pragma unroll
  for (int n = 0; n < 4; ++n) acc[n] = {0.f, 0.f, 0.f, 0.f};

  for (int kk = 0; kk < H_ / 32; ++kk) {
    const int k0 = kk * 32;
    __syncthreads();
    {
      int row = bx * 64 + wave * 16 + rs;
      gload_lds16((const char*)h + ((size_t)row * H_ + k0) * 2 + c16,
                  (char*)As + wave * 1024);
    }
    {
      int jj = wave * 16 + rs;
      gload_lds16((const char*)w1 + ((size_t)jj * H_ + k0) * 2 + c16,
                  (char*)Bs + wave * 1024);
    }
    __syncthreads();
    bf16x8 a = *(const bf16x8*)&As[(wave * 16 + (lane & 15)) * 32 + rdslot];
#pragma unroll
    for (int n = 0; n < 4; ++n) {
      bf16x8 b = *(const bf16x8*)&Bs[(n * 16 + (lane & 15)) * 32 + rdslot];
      acc[n] = __builtin_amdgcn_mfma_f32_16x16x32_bf16(a, b, acc[n], 0, 0, 0);
    }
  }

  const int r0 = (lane >> 4) * 4, cl = lane & 15;
#pragma unroll
  for (int n = 0; n < 4; ++n)
#pragma unroll
    for (int j = 0; j < 4; ++j) {
      int row = wave * 16 + r0 + j;     // local row 0..63
      int col = n * 16 + cl;            // hidden unit 0..63
      hid[row][col] = fmaxf(acc[n][j] + b1[col], 0.0f);
    }
  __syncthreads();

  if (tid < 128) {
    int r = tid >> 1, d = tid & 1;
    float s = b2[d];
#pragma unroll 8
    for (int k2 = 0; k2 < 64; ++k2) s += hid[r][k2] * w2[d * 64 + k2];
    delta[((size_t)(bx * 64 + r) * T_ + t) * 2 + d] = s;
  }
}

// ---------------- final cumsum over T + last_pos ----------------

__global__ void k_cumsum(const float* __restrict__ delta,
                         const float* __restrict__ lp, float* __restrict__ out) {
  int id = blockIdx.x * blockDim.x + threadIdx.x;
  if (id >= B_ * 2) return;
  int b = id >> 1, d = id & 1;
  float cum = lp[b * 2 + d];
  size_t base = (size_t)b * T_ * 2 + d;
  for (int t = 0; t < T_; ++t) {
    cum += delta[base + t * 2];
    out[base + t * 2] = cum;
  }
}

// ---------------- launch ----------------

extern "C" void kernel_launch(void* const* d_in, const int* in_sizes, int n_in,
                              void* d_out, int out_size, void* d_ws, size_t ws_size,
                              hipStream_t stream) {
  const float* z   = (const float*)d_in[0];
  const float* lv  = (const float*)d_in[1];
  const float* lp  = (const float*)d_in[2];
  const float* Wih = (const float*)d_in[3];
  const float* Whh = (const float*)d_in[4];
  const float* bih = (const float*)d_in[5];
  const float* bhh = (const float*)d_in[6];
  const float* W1  = (const float*)d_in[7];
  const float* b1  = (const float*)d_in[8];
  const float* W2  = (const float*)d_in[9];
  const float* b2  = (const float*)d_in[10];
  float* out = (float*)d_out;

  char* ws = (char*)d_ws;
  size_t off = 0;
  u16x4*          xg4    = (u16x4*)(ws + off);          off += (size_t)B_ * H_ * 8;       // 33554432
  unsigned short* whh_bf = (unsigned short*)(ws + off); off += (size_t)G4_ * H_ * 2;      //  8388608
  unsigned short* wih_bf = (unsigned short*)(ws + off); off += (size_t)G4_ * KA_ * 2;     //  8650752
  unsigned short* zaug   = (unsigned short*)(ws + off); off += (size_t)B_ * KA_ * 2;      //  8650752
  unsigned short* w1_bf  = (unsigned short*)(ws + off); off += (size_t)MLPH_ * H_ * 2;    //   131072
  unsigned short* hring  = (unsigned short*)(ws + off); off += (size_t)NB_ * B_ * H_ * 2; // 50331648
  float*          cbuf   = (float*)(ws + off);          off += (size_t)B_ * H_ * 4;       // 16777216
  float*          delta  = (float*)(ws + off);          off += (size_t)B_ * T_ * 2 * 4;   //  1966080
  // total 128450560 bytes

  const size_t BH = (size_t)B_ * H_;

  // zero c and the h(-1) slot (= slot NB_-1 of the ring)
  hipMemsetAsync(hring + (NB_ - 1) * BH, 0, BH * 2, stream);
  hipMemsetAsync(cbuf, 0, BH * 4, stream);

  k_conv_bf16 <<<2048, 256, 0, stream>>>(Whh, whh_bf, G4_ * H_);
  k_conv_wih  <<<2048, 256, 0, stream>>>(Wih, wih_bf);
  k_build_zaug<<<2048, 256, 0, stream>>>(z, lp, lv, zaug);
  k_conv_bf16 <<<256, 256, 0, stream>>>(W1, w1_bf, MLPH_ * H_);

  k_xgates<<<dim3(32, 32), 256, 0, stream>>>(zaug, wih_bf, bih, bhh, xg4);

  for (int t = 0; t < T_; ++t) {
    const unsigned short* hp = hring + (size_t)((t + NB_ - 1) % NB_) * BH;
    unsigned short*       hc = hring + (size_t)(t % NB_) * BH;
    k_step<<<dim3(16, 16), 512, 0, stream>>>(hp, whh_bf, xg4, cbuf, hc);
    if ((t % NB_) == NB_ - 1)
      k_mlp<<<dim3(64, NB_), 256, 0, stream>>>(hring, w1_bf, b1, W2, b2, delta, t - (NB_ - 1));
  }

  k_cumsum<<<32, 256, 0, stream>>>(delta, lp, out);
}